// Round 6
// baseline (1747.674 us; speedup 1.0000x reference)
//
#include <hip/hip_runtime.h>

typedef _Float16 h16;
typedef __attribute__((ext_vector_type(8))) _Float16 half8;
typedef __attribute__((ext_vector_type(4))) float f32x4;
typedef unsigned long long ull;

#define B_   1024
#define T_   256
#define D_   128
#define H_   512
#define Kc_  640    // D + H
#define NR_  2048   // 4H rows, R-mapped
#define AGENT_ __HIP_MEMORY_SCOPE_AGENT

__device__ __forceinline__ float sigm_(float v) {
    return 1.0f / (1.0f + __expf(-v));
}
__device__ __forceinline__ float tanh_(float v) {
    v = fminf(15.0f, fmaxf(-15.0f, v));
    const float e = __expf(2.0f * v);
    return (e - 1.0f) / (e + 1.0f);
}

// Row shuffle: unit j, gate q (torch order i,f,g,o = src row q*512+j):
// R = (j>>2)*16 + (j&3)*4 + q. With C/D row=(lane>>4)*4+reg: reg==gate,
// unit lane-local -> pointwise cell needs no cross-lane.
__global__ void prep_kernel(const float* __restrict__ Wih, const float* __restrict__ Whh,
                            const float* __restrict__ bih, const float* __restrict__ bhh,
                            h16* __restrict__ Wr, float* __restrict__ biasr,
                            unsigned* __restrict__ flags) {
    int idx = blockIdx.x * 256 + threadIdx.x;
    if (idx < NR_ * Kc_) {
        int R = idx / Kc_, k = idx - R * Kc_;
        int Q = R >> 4, rw = R & 15;
        int j = Q * 4 + (rw >> 2), q = rw & 3;
        int src = q * H_ + j;
        float w = (k < D_) ? Wih[src * D_ + k] : Whh[src * H_ + (k - D_)];
        Wr[idx] = (h16)w;
    }
    if (idx < NR_) {
        int Q = idx >> 4, rw = idx & 15;
        int j = Q * 4 + (rw >> 2), q = rw & 3;
        int src = q * H_ + j;
        biasr[idx] = bih[src] + bhh[src];
    }
    if (idx < 8192)   // re-zero flags EVERY launch (graph replay determinism)
        __hip_atomic_store(flags + idx, 0u, __ATOMIC_RELAXED, AGENT_);
}

// Persistent LSTM, cooperative launch (co-residency only; no grid.sync).
// Block (bt = blk>>3, ht = blk&7): batch [bt*32,+32), units [ht*64,+64).
// Batch tile split into halves A (rows 0-15) / B (16-31), pipelined.
// Exchange protocol (all agent-scope RELAXED, L3 = single coherence point):
//   producer: store h slice -> __syncthreads (vmcnt drain) -> store flag = t+1
//   consumer: per-WAVE poll of its one producer's flag -> issue loads ->
//             latency hides under the current half's MFMA compute.
// flags[half][bt][producer]: "count of completed halves", re-zeroed per launch.
__global__ void __launch_bounds__(512, 2) lstm_kernel(
    const float* __restrict__ x,      // [B][T][D] fp32
    const h16*  __restrict__ Wr,      // [2048][640] fp16 (R-mapped)
    const float* __restrict__ biasr,  // [2048]
    h16* __restrict__ hbuf,           // [2][B][H] fp16 double buffer
    unsigned* __restrict__ flags)     // [2][32][8*16] uints
{
    __shared__ __align__(16) char ldsx[8192];     // [32 rows][16 gran16] x tile
    __shared__ __align__(16) char ldshA[16384];   // [16 rows][64 gran16] h half A
    __shared__ __align__(16) char ldshB[16384];
    __shared__ __align__(16) char ldsbA[2048];    // bounce [16 rows][64 u]*2B
    __shared__ __align__(16) char ldsbB[2048];

    const int blk = blockIdx.x;
    const int bt  = blk >> 3;          // 0..31 batch tile
    const int ht  = blk & 7;           // 0..7  unit tile
    const int tid = threadIdx.x;
    const int wv  = tid >> 6, l = tid & 63;
    const int ll  = l & 15, lh = l >> 4;
    const int Rb  = ht * 256 + wv * 32;   // wave's R-row base
    const int bbase = bt * 32;

    // ---- W slice -> registers (once, reused all 256 steps) ----
    half8 warr[2][20];
#pragma unroll
    for (int rt = 0; rt < 2; ++rt) {
        const h16* wbase = Wr + (size_t)(Rb + rt * 16 + ll) * Kc_ + lh * 8;
#pragma unroll
        for (int kc = 0; kc < 20; ++kc)
            warr[rt][kc] = *reinterpret_cast<const half8*>(wbase + kc * 32);
    }
    f32x4 bias4[2];
#pragma unroll
    for (int rt = 0; rt < 2; ++rt)
        bias4[rt] = *reinterpret_cast<const f32x4*>(biasr + Rb + rt * 16 + lh * 4);

    float cstA[2] = {0.f, 0.f}, cstB[2] = {0.f, 0.f};

    // x staging ids: thread (srow 0..31, scol 0..15), Gray+XOR swizzle
    const int srow = tid >> 4, scol = tid & 15;
    const int sgb  = bbase + srow;
    const int xw_byte = (srow * 256 + ((scol ^ (scol >> 1)) * 16)) ^ ((srow & 7) << 4);

    // per-wave h slice ids: wave wv loads/stages producer wv's 64-unit strip
    const int hrow = l >> 2;              // 0..15 (batch row within half)
    const int hquad = l & 3;              // 0..3  (32B quad within 128B strip)

    unsigned* fA = flags + bt * 128;          // [8 producers x 16]
    unsigned* fB = flags + 4096 + bt * 128;
    unsigned* myfA = fA + ht * 16;
    unsigned* myfB = fB + ht * 16;
    unsigned* wfA  = fA + wv * 16;            // this wave's producer
    unsigned* wfB  = fB + wv * 16;

    ull   hvA[4], hvB[4];
    f32x4 xr0, xr1;

    auto loadSlice = [&](const h16* hsrc, int rowoff, ull hv[4]) {
        const ull* hp = reinterpret_cast<const ull*>(
            hsrc + (size_t)(bbase + rowoff + hrow) * H_ + wv * 64);
#pragma unroll
        for (int i = 0; i < 4; ++i)
            hv[i] = __hip_atomic_load(hp + i * 4 + hquad, __ATOMIC_RELAXED, AGENT_);
    };
    auto stageSlice = [&](char* ldsh, const ull hv[4]) {
#pragma unroll
        for (int i = 0; i < 4; ++i) {
            const int u  = wv * 64 + i * 16 + hquad * 4;   // local unit 0..511
            const int g  = u >> 3, hf = (u >> 2) & 1;
            const int g2 = g ^ (g >> 1);
            const int byte = (hrow * 1024 + g2 * 16 + hf * 8) ^ ((hrow & 7) << 4);
            *reinterpret_cast<ull*>(ldsh + byte) = hv[i];
        }
    };
    auto waitFlag = [&](unsigned* f, unsigned tgt) {
        // wave-uniform spin; all lanes load the same address (broadcast)
        while (__hip_atomic_load(f, __ATOMIC_RELAXED, AGENT_) < tgt)
            __builtin_amdgcn_s_sleep(1);
        asm volatile("" ::: "memory");   // keep data loads after the poll
    };
    auto computeHalf = [&](const char* ldsh, int ctbase, f32x4 acc[2]) {
#pragma unroll
        for (int kk = 0; kk < 4; ++kk) {           // x part: k = 0..128
            const int brow = ctbase + ll;
            const int ks = kk * 4 + lh;
            const int g2 = ks ^ (ks >> 1);
            const int byte = (brow * 256 + g2 * 16) ^ ((brow & 7) << 4);
            half8 bf = *reinterpret_cast<const half8*>(ldsx + byte);
#pragma unroll
            for (int rt = 0; rt < 2; ++rt)
                acc[rt] = __builtin_amdgcn_mfma_f32_16x16x32_f16(
                    warr[rt][kk], bf, acc[rt], 0, 0, 0);
        }
#pragma unroll
        for (int kk = 0; kk < 16; ++kk) {          // h part: k = 128..640
            const int ks = kk * 4 + lh;
            const int g2 = ks ^ (ks >> 1);
            const int byte = (ll * 1024 + g2 * 16) ^ ((ll & 7) << 4);
            half8 bf = *reinterpret_cast<const half8*>(ldsh + byte);
#pragma unroll
            for (int rt = 0; rt < 2; ++rt)
                acc[rt] = __builtin_amdgcn_mfma_f32_16x16x32_f16(
                    warr[rt][4 + kk], bf, acc[rt], 0, 0, 0);
        }
    };
    auto cellHalf = [&](f32x4 acc[2], float cst[2], char* ldsb) {
#pragma unroll
        for (int rt = 0; rt < 2; ++rt) {
            f32x4 g4 = acc[rt];
            const float gi = sigm_(g4[0]);
            const float gf = sigm_(g4[1]);
            const float gg = tanh_(g4[2]);
            const float go = sigm_(g4[3]);
            const float c  = gf * cst[rt] + gi * gg;
            cst[rt] = c;
            const float hn = go * tanh_(c);
            const int u = wv * 8 + rt * 4 + lh;
            const int byte = (ll * 128 + u * 2) ^ ((ll & 7) << 4);
            *reinterpret_cast<h16*>(ldsb + byte) = (h16)hn;
        }
    };
    auto storeHalf = [&](const char* ldsb, h16* hcur, int rowoff) {
        if (tid < 256) {
            const int r2 = tid >> 4, c2 = tid & 15;
            const int byte = (r2 * 128 + c2 * 8) ^ ((r2 & 7) << 4);
            ull pk = *reinterpret_cast<const ull*>(ldsb + byte);
            ull* dst = reinterpret_cast<ull*>(
                hcur + (size_t)(bbase + rowoff + r2) * H_ + ht * 64 + c2 * 4);
            __hip_atomic_store(dst, pk, __ATOMIC_RELAXED, AGENT_);
        }
    };

    // ---- prologue: zero both h tiles, load+stage x(0) ----
    {
        half8 z;
#pragma unroll
        for (int u = 0; u < 8; ++u) z[u] = (h16)0.f;
        char* pA = ldshA + tid * 32;
        char* pB = ldshB + tid * 32;
        *reinterpret_cast<half8*>(pA) = z; *reinterpret_cast<half8*>(pA + 16) = z;
        *reinterpret_cast<half8*>(pB) = z; *reinterpret_cast<half8*>(pB + 16) = z;
        const float* xp = x + (size_t)sgb * T_ * D_ + scol * 8;
        xr0 = *reinterpret_cast<const f32x4*>(xp);
        xr1 = *reinterpret_cast<const f32x4*>(xp + 4);
        half8 r;
#pragma unroll
        for (int u = 0; u < 4; ++u) { r[u] = (h16)xr0[u]; r[4 + u] = (h16)xr1[u]; }
        *reinterpret_cast<half8*>(ldsx + xw_byte) = r;
    }
    __syncthreads();

    for (int t = 0; t < T_; ++t) {
        h16* hcur        = hbuf + (size_t)(t & 1) * (B_ * H_);
        const h16* hprev = hbuf + (size_t)((t & 1) ^ 1) * (B_ * H_);

        // issue x(t+1) prefetch first (independent of everything)
        if (t + 1 < T_) {
            const float* xp = x + ((size_t)sgb * T_ + (t + 1)) * D_ + scol * 8;
            xr0 = *reinterpret_cast<const f32x4*>(xp);
            xr1 = *reinterpret_cast<const f32x4*>(xp + 4);
        }
        // poll producer flag for h_B(t-1), issue loads: latency hides under A
        if (t > 0) {
            waitFlag(wfB, (unsigned)t);
            loadSlice(hprev, 16, hvB);
        }

        // ================= half A =================
        f32x4 acc[2];
        acc[0] = bias4[0]; acc[1] = bias4[1];
        computeHalf(ldshA, 0, acc);
        cellHalf(acc, cstA, ldsbA);
        __syncthreads();                                   // S2A
        storeHalf(ldsbA, hcur, 0);
        if (t > 0) stageSlice(ldshB, hvB);                 // hvB arrived under A
        __syncthreads();                                   // S3A: drains stores+stage
        if (tid == 0)
            __hip_atomic_store(myfA, (unsigned)(t + 1), __ATOMIC_RELAXED, AGENT_);

        // poll producer flag for h_A(t), issue loads: latency hides under B
        if (t + 1 < T_) {
            waitFlag(wfA, (unsigned)(t + 1));
            loadSlice(hcur, 0, hvA);
        }

        // ================= half B =================
        acc[0] = bias4[0]; acc[1] = bias4[1];
        computeHalf(ldshB, 16, acc);
        cellHalf(acc, cstB, ldsbB);
        __syncthreads();                                   // S2B
        storeHalf(ldsbB, hcur, 16);
        if (t + 1 < T_) {
            half8 r;                                       // stage x(t+1)
#pragma unroll
            for (int u = 0; u < 4; ++u) { r[u] = (h16)xr0[u]; r[4 + u] = (h16)xr1[u]; }
            *reinterpret_cast<half8*>(ldsx + xw_byte) = r;
            stageSlice(ldshA, hvA);                        // hvA arrived under B
        }
        __syncthreads();                                   // S3B: drains stores+stage
        if (tid == 0)
            __hip_atomic_store(myfB, (unsigned)(t + 1), __ATOMIC_RELAXED, AGENT_);
    }
}

// features = hT @ Wfeat^T + bfeat ; out = features @ Wout^T + bout
__global__ void __launch_bounds__(256) final_kernel(
    const h16* __restrict__ hT, const float* __restrict__ Wfeat,
    const float* __restrict__ bfeat, const float* __restrict__ Wout,
    const float* __restrict__ bout, float* __restrict__ out)
{
    __shared__ __align__(16) h16 hsh[16][512];
    __shared__ float fsh[16][256];
    const int tid = threadIdx.x;
    const int b0  = blockIdx.x * 16;

    {
        const int row = tid >> 4, seg = tid & 15;
        const half8* s8 = reinterpret_cast<const half8*>(hT + (size_t)(b0 + row) * H_ + seg * 32);
        half8* d8 = reinterpret_cast<half8*>(&hsh[row][seg * 32]);
        d8[0] = s8[0]; d8[1] = s8[1]; d8[2] = s8[2]; d8[3] = s8[3];
    }
    __syncthreads();

    float acc[16];
#pragma unroll
    for (int b = 0; b < 16; ++b) acc[b] = 0.f;
    const float* wrow = Wfeat + (size_t)tid * H_;
    for (int k8 = 0; k8 < H_ / 8; ++k8) {
        f32x4 w0 = *reinterpret_cast<const f32x4*>(wrow + k8 * 8);
        f32x4 w1 = *reinterpret_cast<const f32x4*>(wrow + k8 * 8 + 4);
#pragma unroll
        for (int b = 0; b < 16; ++b) {
            half8 h8 = *reinterpret_cast<const half8*>(&hsh[b][k8 * 8]);
#pragma unroll
            for (int u = 0; u < 4; ++u) {
                acc[b] = fmaf(w0[u], (float)h8[u], acc[b]);
                acc[b] = fmaf(w1[u], (float)h8[4 + u], acc[b]);
            }
        }
    }
    const float bf = bfeat[tid];
#pragma unroll
    for (int b = 0; b < 16; ++b) fsh[b][tid] = acc[b] + bf;
    __syncthreads();

    if (tid < 32) {
        const int b = tid >> 1, oc = tid & 1;
        float a = bout[oc];
        const float* wo = Wout + oc * 256;
        for (int f = 0; f < 256; ++f) a = fmaf(wo[f], fsh[b][f], a);
        out[(size_t)(b0 + b) * 2 + oc] = a;
    }
}

extern "C" void kernel_launch(void* const* d_in, const int* in_sizes, int n_in,
                              void* d_out, int out_size, void* d_ws, size_t ws_size,
                              hipStream_t stream) {
    const float* x     = (const float*)d_in[0];
    const float* Wih   = (const float*)d_in[1];
    const float* Whh   = (const float*)d_in[2];
    const float* bih   = (const float*)d_in[3];
    const float* bhh   = (const float*)d_in[4];
    const float* Wfeat = (const float*)d_in[5];
    const float* bfeat = (const float*)d_in[6];
    const float* Wout  = (const float*)d_in[7];
    const float* bout  = (const float*)d_in[8];
    float* out = (float*)d_out;

    char* ws = (char*)d_ws;
    h16*      Wr    = (h16*)ws;                          // 2,621,440 B
    float*    biasr = (float*)(ws + 2621440);            // 8,192 B
    h16*      hbuf  = (h16*)(ws + 2621440 + 8192);       // 2,097,152 B
    unsigned* flags = (unsigned*)(ws + 2621440 + 8192 + 2097152);  // 32,768 B

    prep_kernel<<<dim3((NR_ * Kc_ + 255) / 256), dim3(256), 0, stream>>>(
        Wih, Whh, bih, bhh, Wr, biasr, flags);

    void* args[] = {(void*)&x, (void*)&Wr, (void*)&biasr, (void*)&hbuf, (void*)&flags};
    hipLaunchCooperativeKernel((void*)lstm_kernel, dim3(256), dim3(512), args, 0, stream);

    const h16* hT = hbuf + (size_t)(B_ * H_);   // slot (T-1)&1 == 1
    final_kernel<<<dim3(B_ / 16), dim3(256), 0, stream>>>(hT, Wfeat, bfeat, Wout, bout, out);
}

// Round 9
// 1182.785 us; speedup vs baseline: 1.4776x; 1.4776x over previous
//
#include <hip/hip_runtime.h>

typedef _Float16 h16;
typedef __attribute__((ext_vector_type(8))) _Float16 half8;
typedef __attribute__((ext_vector_type(4))) float f32x4;
typedef __attribute__((ext_vector_type(4))) unsigned u32x4;
typedef unsigned long long ull;

#define B_   1024
#define T_   256
#define D_   128
#define H_   512
#define Kc_  640    // D + H
#define NR_  2048   // 4H rows, R-mapped
#define AGENT_ __HIP_MEMORY_SCOPE_AGENT

__device__ __forceinline__ float sigm_(float v) {
    return 1.0f / (1.0f + __expf(-v));
}
__device__ __forceinline__ float tanh_(float v) {
    v = fminf(15.0f, fmaxf(-15.0f, v));
    const float e = __expf(2.0f * v);
    return (e - 1.0f) / (e + 1.0f);
}

// Row shuffle: unit j, gate q (torch order i,f,g,o = src row q*512+j):
// R = (j>>2)*16 + (j&3)*4 + q. With C/D row=(lane>>4)*4+reg: reg==gate,
// unit lane-local -> pointwise cell needs no cross-lane.
__global__ void prep_kernel(const float* __restrict__ Wih, const float* __restrict__ Whh,
                            const float* __restrict__ bih, const float* __restrict__ bhh,
                            h16* __restrict__ Wr, float* __restrict__ biasr,
                            unsigned* __restrict__ flags) {
    int idx = blockIdx.x * 256 + threadIdx.x;
    if (idx < NR_ * Kc_) {
        int R = idx / Kc_, k = idx - R * Kc_;
        int Q = R >> 4, rw = R & 15;
        int j = Q * 4 + (rw >> 2), q = rw & 3;
        int src = q * H_ + j;
        float w = (k < D_) ? Wih[src * D_ + k] : Whh[src * H_ + (k - D_)];
        Wr[idx] = (h16)w;
    }
    if (idx < NR_) {
        int Q = idx >> 4, rw = idx & 15;
        int j = Q * 4 + (rw >> 2), q = rw & 3;
        int src = q * H_ + j;
        biasr[idx] = bih[src] + bhh[src];
    }
    // re-zero flags[32][512] EVERY launch (graph replay determinism)
    if (idx < 16384)
        __hip_atomic_store(flags + idx, 0u, __ATOMIC_RELAXED, AGENT_);
}

// Persistent LSTM, cooperative launch (co-residency only). NO placement
// assumptions: group = blockIdx-based, exchange agent-scope through L3
// (proven-correct R5/R6 path). Block (bt=blk>>3, ht=blk&7): batch
// [bt*32,+32), units [ht*64,+64). Batch tile split into halves A(0-15)/
// B(16-31): per-half flag poll + h loads are ISSUED inside the other
// half's compute (split inline-asm issue/waitcnt), so the L3 round trip
// hides under MFMA work. W slice pinned in 160 VGPRs for all 256 steps.
// Deadlock-free: flags stored unconditionally every phase; phase-A waits
// on prior-step phase-B flags, phase-B waits on same-step phase-A flags.
__global__ void __launch_bounds__(512, 2) lstm_kernel(
    const float* __restrict__ x,      // [B][T][D] fp32
    const h16*  __restrict__ Wr,      // [2048][640] fp16 (R-mapped)
    const float* __restrict__ biasr,  // [2048]
    h16* __restrict__ hbuf,           // [2][B][H] fp16 double buffer
    unsigned* __restrict__ flags)     // [32 groups][2 phases][8 prod x 32]
{
    __shared__ __align__(16) char ldsx[8192];     // [32 rows][128 k] fp16, swizzled
    __shared__ __align__(16) char ldshA[16384];   // [16 rows][512 k] fp16 half A
    __shared__ __align__(16) char ldshB[16384];
    __shared__ __align__(16) char ldsb[2048];     // bounce [16 rows][64 u] fp16

    const int blk = blockIdx.x;
    const int bt  = blk >> 3;          // 0..31 batch tile (group)
    const int ht  = blk & 7;           // 0..7  unit tile
    const int tid = threadIdx.x;
    const int wv  = tid >> 6, l = tid & 63;
    const int ll  = l & 15, lh = l >> 4;
    const int Rb  = ht * 256 + wv * 32;
    const int bbase = bt * 32;

    // ---- W slice -> registers, PINNED (defeat rematerialization) ----
    half8 warr[2][20];
#pragma unroll
    for (int rt = 0; rt < 2; ++rt) {
        const h16* wbase = Wr + (size_t)(Rb + rt * 16 + ll) * Kc_ + lh * 8;
#pragma unroll
        for (int kc = 0; kc < 20; ++kc)
            warr[rt][kc] = *reinterpret_cast<const half8*>(wbase + kc * 32);
    }
#pragma unroll
    for (int rt = 0; rt < 2; ++rt)
#pragma unroll
        for (int kc = 0; kc < 20; ++kc)
            asm volatile("" : "+v"(warr[rt][kc]));
    f32x4 bias4[2];
#pragma unroll
    for (int rt = 0; rt < 2; ++rt)
        bias4[rt] = *reinterpret_cast<const f32x4*>(biasr + Rb + rt * 16 + lh * 4);

    float cstA[2] = {0.f, 0.f}, cstB[2] = {0.f, 0.f};

    // staging ids
    const int xrow = tid >> 4, xcol = tid & 15;   // x: 32 rows x 16 cols x 32B(fp32)
    const int hrow = tid >> 5, hcol = tid & 31;   // h: 16 rows x 32 cols x 32B

    unsigned* fbase = flags + bt * 512;
    unsigned* myfA  = fbase + ht * 32;
    unsigned* myfB  = fbase + 256 + ht * 32;
    const unsigned* wfpA = fbase + (l & 7) * 32;        // lane polls producer l&7
    const unsigned* wfpB = fbase + 256 + (l & 7) * 32;

    unsigned fv = 0;
    f32x4 xv0, xv1;
    u32x4 hv0, hv1;

    auto issueFlag = [&](const unsigned* p) {
        asm volatile("global_load_dword %0, %1, off sc0 sc1" : "=v"(fv) : "v"(p));
    };
    auto issueX = [&](int t) {
        const float* xp = x + ((size_t)(bbase + xrow) * T_ + t) * D_ + xcol * 8;
        asm volatile("global_load_dwordx4 %0, %2, off\n\t"
                     "global_load_dwordx4 %1, %2, off offset:16"
                     : "=&v"(xv0), "=&v"(xv1) : "v"(xp));
    };
    auto issueH = [&](const h16* hsrc, int rowoff) {
        const char* hp = (const char*)(hsrc + (size_t)(bbase + rowoff + hrow) * H_) + hcol * 32;
        asm volatile("global_load_dwordx4 %0, %2, off sc0 sc1\n\t"
                     "global_load_dwordx4 %1, %2, off offset:16 sc0 sc1"
                     : "=&v"(hv0), "=&v"(hv1) : "v"(hp) : "memory");
    };
    auto spinFlag = [&](unsigned tgt, const unsigned* p) {
        while (!__all(fv >= tgt)) {
            __builtin_amdgcn_s_sleep(2);
            asm volatile("global_load_dword %0, %1, off sc0 sc1\n\ts_waitcnt vmcnt(0)"
                         : "=v"(fv) : "v"(p) : "memory");
        }
    };
    auto stageX = [&]() {
        half8 r;
#pragma unroll
        for (int u = 0; u < 4; ++u) { r[u] = (h16)xv0[u]; r[4 + u] = (h16)xv1[u]; }
        *reinterpret_cast<half8*>(ldsx + ((xrow * 256 + xcol * 16) ^ ((xrow & 7) << 4))) = r;
    };
    auto stageH = [&](char* ldsh) {
        const int swz = (hrow & 7) << 4;
        const int g0 = hcol * 2, g1 = hcol * 2 + 1;
        *reinterpret_cast<u32x4*>(ldsh + ((hrow * 1024 + (g0 ^ (g0 >> 1)) * 16) ^ swz)) = hv0;
        *reinterpret_cast<u32x4*>(ldsh + ((hrow * 1024 + (g1 ^ (g1 >> 1)) * 16) ^ swz)) = hv1;
    };
    auto computeX = [&](int rowoff, f32x4* acc) {
#pragma unroll
        for (int kk = 0; kk < 4; ++kk) {
            const int row = rowoff + ll;
            half8 bf = *reinterpret_cast<const half8*>(
                ldsx + ((row * 256 + (kk * 4 + lh) * 16) ^ ((row & 7) << 4)));
            acc[0] = __builtin_amdgcn_mfma_f32_16x16x32_f16(warr[0][kk], bf, acc[0], 0, 0, 0);
            acc[1] = __builtin_amdgcn_mfma_f32_16x16x32_f16(warr[1][kk], bf, acc[1], 0, 0, 0);
        }
    };
    auto computeH_lo = [&](const char* ldsh, f32x4* acc) {
#pragma unroll
        for (int kk = 0; kk < 8; ++kk) {
            const int ks = kk * 4 + lh;
            half8 bf = *reinterpret_cast<const half8*>(
                ldsh + ((ll * 1024 + (ks ^ (ks >> 1)) * 16) ^ ((ll & 7) << 4)));
            acc[0] = __builtin_amdgcn_mfma_f32_16x16x32_f16(warr[0][4 + kk], bf, acc[0], 0, 0, 0);
            acc[1] = __builtin_amdgcn_mfma_f32_16x16x32_f16(warr[1][4 + kk], bf, acc[1], 0, 0, 0);
        }
    };
    auto computeH_hi = [&](const char* ldsh, f32x4* acc) {
#pragma unroll
        for (int kk = 8; kk < 16; ++kk) {
            const int ks = kk * 4 + lh;
            half8 bf = *reinterpret_cast<const half8*>(
                ldsh + ((ll * 1024 + (ks ^ (ks >> 1)) * 16) ^ ((ll & 7) << 4)));
            acc[0] = __builtin_amdgcn_mfma_f32_16x16x32_f16(warr[0][4 + kk], bf, acc[0], 0, 0, 0);
            acc[1] = __builtin_amdgcn_mfma_f32_16x16x32_f16(warr[1][4 + kk], bf, acc[1], 0, 0, 0);
        }
    };
    auto cellHalf = [&](f32x4* acc, float* cst) {
#pragma unroll
        for (int rt = 0; rt < 2; ++rt) {
            f32x4 g4 = acc[rt];
            const float gi = sigm_(g4[0]);
            const float gf = sigm_(g4[1]);
            const float gg = tanh_(g4[2]);
            const float go = sigm_(g4[3]);
            const float c  = gf * cst[rt] + gi * gg;
            cst[rt] = c;
            const float hn = go * tanh_(c);
            const int u = wv * 8 + rt * 4 + lh;
            *reinterpret_cast<h16*>(ldsb + ((ll * 128 + u * 2) ^ ((ll & 7) << 4))) = (h16)hn;
        }
    };
    auto storeHalf = [&](h16* hcur, int rowoff) {
        if (tid < 256) {
            const int r2 = tid >> 4, c2 = tid & 15;
            ull pk = *reinterpret_cast<const ull*>(
                ldsb + ((r2 * 128 + c2 * 8) ^ ((r2 & 7) << 4)));
            ull* dst = reinterpret_cast<ull*>(
                hcur + (size_t)(bbase + rowoff + r2) * H_ + ht * 64 + c2 * 4);
            __hip_atomic_store(dst, pk, __ATOMIC_RELAXED, AGENT_);
        }
    };

    // ---- prologue: zero both h tiles, load+stage x(0) ----
    {
        half8 z;
#pragma unroll
        for (int u = 0; u < 8; ++u) z[u] = (h16)0.f;
        *reinterpret_cast<half8*>(ldshA + tid * 32)      = z;
        *reinterpret_cast<half8*>(ldshA + tid * 32 + 16) = z;
        *reinterpret_cast<half8*>(ldshB + tid * 32)      = z;
        *reinterpret_cast<half8*>(ldshB + tid * 32 + 16) = z;
        issueX(0);
        asm volatile("s_waitcnt vmcnt(0)" : "+v"(xv0), "+v"(xv1) :: "memory");
        stageX();
    }
    __syncthreads();

    for (int t = 0; t < T_; ++t) {
        h16* hcur        = hbuf + (size_t)(t & 1) * (B_ * H_);
        const h16* hprev = hbuf + (size_t)((t & 1) ^ 1) * (B_ * H_);

        // ========== phase A (rows 0-15, reads ldshA = hA(t-1)) ==========
        if (t > 0) issueFlag(wfpB);                 // oldest outstanding: flag
        issueX(t + 1 < T_ ? t + 1 : t);             // then 2 x loads
        f32x4 acc[2] = {bias4[0], bias4[1]};
        computeX(0, acc);
        computeH_lo(ldshA, acc);
        if (t > 0) {
            // wait ONLY the flag (in-order vmcnt retire; x still in flight)
            asm volatile("s_waitcnt vmcnt(2)" : "+v"(fv) :: "memory");
            if (!__all(fv >= (unsigned)t)) spinFlag((unsigned)t, wfpB);
            issueH(hprev, 16);                      // hB(t-1), hides under hi+cell
        }
        computeH_hi(ldshA, acc);
        cellHalf(acc, cstA);
        __syncthreads();                            // S1
        if (t > 0) {
            // asm loads are invisible to the barrier's auto-drain: explicit wait
            asm volatile("s_waitcnt vmcnt(0)" : "+v"(hv0), "+v"(hv1) :: "memory");
            stageH(ldshB);
        }
        storeHalf(hcur, 0);                         // hA(t) -> L3
        __syncthreads();                            // S2: h stores drained
        if (tid == 0)
            __hip_atomic_store(myfA, (unsigned)(t + 1), __ATOMIC_RELAXED, AGENT_);

        // ========== phase B (rows 16-31, reads ldshB = hB(t-1)) ==========
        issueFlag(wfpA);
        f32x4 accB[2] = {bias4[0], bias4[1]};
        computeX(16, accB);
        computeH_lo(ldshB, accB);
        asm volatile("s_waitcnt vmcnt(0)" : "+v"(fv) :: "memory");
        if (!__all(fv >= (unsigned)(t + 1))) spinFlag((unsigned)(t + 1), wfpA);
        issueH(hcur, 0);                            // hA(t), hides under hi+cell
        computeH_hi(ldshB, accB);
        cellHalf(accB, cstB);
        __syncthreads();                            // S3
        asm volatile("s_waitcnt vmcnt(0)"
                     : "+v"(hv0), "+v"(hv1), "+v"(xv0), "+v"(xv1) :: "memory");
        stageH(ldshA);                              // hA(t) for step t+1
        stageX();                                   // x(t+1)
        storeHalf(hcur, 16);                        // hB(t) -> L3
        __syncthreads();                            // S4: drained
        if (tid == 0)
            __hip_atomic_store(myfB, (unsigned)(t + 1), __ATOMIC_RELAXED, AGENT_);
    }
}

// features = hT @ Wfeat^T + bfeat ; out = features @ Wout^T + bout
__global__ void __launch_bounds__(256) final_kernel(
    const h16* __restrict__ hT, const float* __restrict__ Wfeat,
    const float* __restrict__ bfeat, const float* __restrict__ Wout,
    const float* __restrict__ bout, float* __restrict__ out)
{
    __shared__ __align__(16) h16 hsh[16][512];
    __shared__ float fsh[16][256];
    const int tid = threadIdx.x;
    const int b0  = blockIdx.x * 16;

    {
        const int row = tid >> 4, seg = tid & 15;
        const half8* s8 = reinterpret_cast<const half8*>(hT + (size_t)(b0 + row) * H_ + seg * 32);
        half8* d8 = reinterpret_cast<half8*>(&hsh[row][seg * 32]);
        d8[0] = s8[0]; d8[1] = s8[1]; d8[2] = s8[2]; d8[3] = s8[3];
    }
    __syncthreads();

    float acc[16];
#pragma unroll
    for (int b = 0; b < 16; ++b) acc[b] = 0.f;
    const float* wrow = Wfeat + (size_t)tid * H_;
    for (int k8 = 0; k8 < H_ / 8; ++k8) {
        f32x4 w0 = *reinterpret_cast<const f32x4*>(wrow + k8 * 8);
        f32x4 w1 = *reinterpret_cast<const f32x4*>(wrow + k8 * 8 + 4);
#pragma unroll
        for (int b = 0; b < 16; ++b) {
            half8 h8 = *reinterpret_cast<const half8*>(&hsh[b][k8 * 8]);
#pragma unroll
            for (int u = 0; u < 4; ++u) {
                acc[b] = fmaf(w0[u], (float)h8[u], acc[b]);
                acc[b] = fmaf(w1[u], (float)h8[4 + u], acc[b]);
            }
        }
    }
    const float bf = bfeat[tid];
#pragma unroll
    for (int b = 0; b < 16; ++b) fsh[b][tid] = acc[b] + bf;
    __syncthreads();

    if (tid < 32) {
        const int b = tid >> 1, oc = tid & 1;
        float a = bout[oc];
        const float* wo = Wout + oc * 256;
        for (int f = 0; f < 256; ++f) a = fmaf(wo[f], fsh[b][f], a);
        out[(size_t)(b0 + b) * 2 + oc] = a;
    }
}

extern "C" void kernel_launch(void* const* d_in, const int* in_sizes, int n_in,
                              void* d_out, int out_size, void* d_ws, size_t ws_size,
                              hipStream_t stream) {
    const float* x     = (const float*)d_in[0];
    const float* Wih   = (const float*)d_in[1];
    const float* Whh   = (const float*)d_in[2];
    const float* bih   = (const float*)d_in[3];
    const float* bhh   = (const float*)d_in[4];
    const float* Wfeat = (const float*)d_in[5];
    const float* bfeat = (const float*)d_in[6];
    const float* Wout  = (const float*)d_in[7];
    const float* bout  = (const float*)d_in[8];
    float* out = (float*)d_out;

    char* ws = (char*)d_ws;
    h16*      Wr    = (h16*)ws;                          // 2,621,440 B
    float*    biasr = (float*)(ws + 2621440);            // 8,192 B
    h16*      hbuf  = (h16*)(ws + 2621440 + 8192);       // 2,097,152 B
    unsigned* flags = (unsigned*)(ws + 2621440 + 8192 + 2097152);  // 65,536 B

    prep_kernel<<<dim3((NR_ * Kc_ + 255) / 256), dim3(256), 0, stream>>>(
        Wih, Whh, bih, bhh, Wr, biasr, flags);

    void* args[] = {(void*)&x, (void*)&Wr, (void*)&biasr, (void*)&hbuf, (void*)&flags};
    hipLaunchCooperativeKernel((void*)lstm_kernel, dim3(256), dim3(512), args, 0, stream);

    const h16* hT = hbuf + (size_t)(B_ * H_);   // slot (T-1)&1 == 1
    final_kernel<<<dim3(B_ / 16), dim3(256), 0, stream>>>(hT, Wfeat, bfeat, Wout, bout, out);
}